// Round 11
// baseline (315.215 us; speedup 1.0000x reference)
//
#include <hip/hip_runtime.h>
#include <hip/hip_bf16.h>
#include <stdint.h>

#define FDIM 128
#define CDIM 10

typedef unsigned short u16;
typedef unsigned char u8;
typedef __attribute__((ext_vector_type(8))) short short8;   // 8 bf16 (4 VGPRs) — MFMA A/B frag
typedef __attribute__((ext_vector_type(4))) float f32x4;    // MFMA C/D frag
typedef __attribute__((ext_vector_type(2))) float f32x2;

__device__ inline u16 f2bf(float f) {
    unsigned int u = __float_as_uint(f);
    u += 0x7fff + ((u >> 16) & 1);  // round-to-nearest-even
    return (u16)(u >> 16);
}
__device__ inline unsigned int pack2(float a, float b) {
    return (unsigned int)f2bf(a) | ((unsigned int)f2bf(b) << 16);
}
// accumulate 4 fp8 (one uint) into two f32x2 accs via hw cvt
__device__ inline void acc_fp8x4(f32x2& a0, f32x2& a1, unsigned u) {
    a0 += __builtin_amdgcn_cvt_pk_f32_fp8(u, false);
    a1 += __builtin_amdgcn_cvt_pk_f32_fp8(u, true);
}
// pack 4 f32 -> 4 fp8 bytes (one uint)
__device__ inline unsigned pk_fp8x4(float a, float b, float c, float d) {
    unsigned o = 0;
    o = __builtin_amdgcn_cvt_pk_fp8_f32(a, b, o, false);
    o = __builtin_amdgcn_cvt_pk_fp8_f32(c, d, o, true);
    return o;
}

// ---------------- utility ----------------

__global__ void sentinel_kernel(float* __restrict__ out, int n, float val) {
    int i = blockIdx.x * blockDim.x + threadIdx.x;
    if (i < n) out[i] = val;
}

// blocks 0..191: W[128][128] fp32 -> WbT[n][k] bf16 for 3 matrices
// block 192: zero row N of both fp8 tables; block 193: zero bcnt
__global__ void wconv_kernel(const float* __restrict__ W1, const float* __restrict__ W2,
                             const float* __restrict__ W3, u16* __restrict__ wbt,
                             unsigned* __restrict__ hs8A_rowN, unsigned* __restrict__ hs8B_rowN,
                             int* __restrict__ bcnt, int NB) {
    int tid = threadIdx.x;
    if (blockIdx.x == 192) {
        if (tid < FDIM / 4) { hs8A_rowN[tid] = 0; hs8B_rowN[tid] = 0; }
        return;
    }
    if (blockIdx.x == 193) {
        for (int i = tid; i < NB; i += 256) bcnt[i] = 0;
        return;
    }
    int which = blockIdx.x >> 6;
    int i = (blockIdx.x & 63) * 256 + tid;
    const float* W = which == 0 ? W1 : (which == 1 ? W2 : W3);
    int k = i >> 7, n = i & 127;
    wbt[(size_t)which * 16384 + n * 128 + k] = f2bf(W[k * 128 + n]);
}

// x fp32 -> fp8 pre-scaled by dinv (4 elems/thread); row N already zeroed by wconv
__global__ void xconv_kernel(const float* __restrict__ x, const float* __restrict__ dinv,
                             u8* __restrict__ hs8A, int N) {
    int i = (blockIdx.x * blockDim.x + threadIdx.x) * 4;
    if (i < N * FDIM) {
        int v = i >> 7;
        float dv = dinv[v];
        float4 f = *(const float4*)&x[i];
        ((unsigned*)hs8A)[i >> 2] = pk_fp8x4(dv * f.x, dv * f.y, dv * f.z, dv * f.w);
    }
}

// ---------------- bucketed CSR build ----------------
// buckets of 128 nodes: b = dst >> 7.  NB = ceil(N/128) <= 1024.
// ebuf entry packed: (dst & 127) << 25 | src   (requires N <= 2^25)

#define ECHUNK 2048

__global__ __launch_bounds__(256) void count_kernel(const int* __restrict__ dst, int E,
                                                    int* __restrict__ bcnt, int NB) {
    __shared__ int lc[1024];
    int tid = threadIdx.x;
    for (int i = tid; i < NB; i += 256) lc[i] = 0;
    __syncthreads();
    int base = blockIdx.x * ECHUNK;
    int lim = min(base + ECHUNK, E);
    for (int i = base + tid; i < lim; i += 256)
        atomicAdd(&lc[dst[i] >> 7], 1);
    __syncthreads();
    for (int i = tid; i < NB; i += 256)
        if (lc[i]) atomicAdd(&bcnt[i], lc[i]);
}

__global__ __launch_bounds__(1024) void scan_kernel(const int* __restrict__ bcnt, int NB, int E,
                                                    int* __restrict__ boff, int* __restrict__ bcursor) {
    __shared__ int s[1024];
    int tid = threadIdx.x;
    s[tid] = (tid < NB) ? bcnt[tid] : 0;
    __syncthreads();
    for (int off = 1; off < 1024; off <<= 1) {
        int v = (tid >= off) ? s[tid - off] : 0;
        __syncthreads();
        s[tid] += v;
        __syncthreads();
    }
    int excl = tid ? s[tid - 1] : 0;
    if (tid < NB) { boff[tid] = excl; bcursor[tid] = excl; }
    if (tid == 0) boff[NB] = E;
}

__global__ __launch_bounds__(256) void part_kernel(const int* __restrict__ src,
                                                   const int* __restrict__ dst, int E,
                                                   int* __restrict__ bcursor,
                                                   unsigned* __restrict__ ebuf, int NB) {
    __shared__ int lc[1024];
    __shared__ int lbase[1024];
    int tid = threadIdx.x;
    for (int i = tid; i < NB; i += 256) lc[i] = 0;
    __syncthreads();
    int base = blockIdx.x * ECHUNK;
    int lim = min(base + ECHUNK, E);
    for (int i = base + tid; i < lim; i += 256)
        atomicAdd(&lc[dst[i] >> 7], 1);
    __syncthreads();
    for (int i = tid; i < NB; i += 256) {
        int c = lc[i];
        lbase[i] = c ? atomicAdd(&bcursor[i], c) : 0;
        lc[i] = 0;  // reuse as local cursor
    }
    __syncthreads();
    for (int i = base + tid; i < lim; i += 256) {
        int s_ = src[i];
        int d_ = dst[i];
        int b = d_ >> 7;
        int r = atomicAdd(&lc[b], 1);
        ebuf[lbase[b] + r] = ((unsigned)(d_ & 127) << 25) | (unsigned)s_;
    }
}

// one block per 128-node bucket: hist -> scan -> rowp/dinv; scatter colx in bucket window
__global__ __launch_bounds__(256) void build_kernel(const unsigned* __restrict__ ebuf,
                                                    const int* __restrict__ boff,
                                                    int* __restrict__ rowp, float* __restrict__ dinv,
                                                    int* __restrict__ colx, int N, int E) {
    __shared__ int hist[128];
    __shared__ int pfx[128];
    __shared__ int cur[128];
    int b = blockIdx.x;
    int tid = threadIdx.x;
    int ebase = boff[b], eend = boff[b + 1];
    if (tid < 128) hist[tid] = 0;
    __syncthreads();
    for (int i = ebase + tid; i < eend; i += 256)
        atomicAdd(&hist[ebuf[i] >> 25], 1);
    __syncthreads();
    if (tid < 128) {
        int deg = hist[tid];
        pfx[tid] = deg;
    }
    __syncthreads();
    for (int off = 1; off < 128; off <<= 1) {
        int t = 0;
        if (tid < 128 && tid >= off) t = pfx[tid - off];
        __syncthreads();
        if (tid < 128) pfx[tid] += t;
        __syncthreads();
    }
    if (tid < 128) {
        int deg = hist[tid];
        int excl = pfx[tid] - deg;
        int node = b * 128 + tid;
        if (node < N) {
            rowp[node] = ebase + excl;
            dinv[node] = rsqrtf(1.0f + (float)deg);  // +1 self-loop
            if (node == N - 1) rowp[N] = E;
        }
        cur[tid] = ebase + excl;
    }
    __syncthreads();
    for (int i = ebase + tid; i < eend; i += 256) {
        unsigned e = ebuf[i];
        int r = atomicAdd(&cur[e >> 25], 1);
        colx[r] = (int)(e & 0x1FFFFFFu);
    }
}

// ---------------- fused layer: group-per-node gather -> LDS bf16 tile -> MFMA -> epilogue ----
// hs8_in: (N+1) x 128 fp8, row v = dinv[v]*h[v], row N = zeros.
// Gather (geometry = R10 agg, no cross-lane ops): 32 groups x 8 lanes; group owns one node,
// lane covers 16 fp8 (one uint4); 2 passes cover the 64-row tile. agg = dv*(self + sum) packed
// bf16 into As. Then MFMA vs WbT; epilogue writes fp8 next-table (FP8OUT) or bf16 h3.

template <bool FP8OUT>
__global__ __launch_bounds__(256) void layer_kernel(const u8* __restrict__ hs8_in,
                                                    const int* __restrict__ rowp,
                                                    const int* __restrict__ colx,
                                                    const float* __restrict__ dinv,
                                                    const u16* __restrict__ WbT,
                                                    const float* __restrict__ bias,
                                                    u8* __restrict__ out8,
                                                    u16* __restrict__ outbf, int N) {
    __shared__ u16 As[64][136];
    __shared__ u8 As8[64][144];  // fp8 epilogue staging (wave-local rows only)
    int tid = threadIdx.x;
    int w = tid >> 6;
    int l = tid & 63;
    int row0 = blockIdx.x * 64;
    int grp = tid >> 3;   // 0..31
    int c = tid & 7;      // 16B chunk within row
    const uint4* h4 = (const uint4*)hs8_in;

    // ---- gather phase: 2 passes x 32 nodes ----
#pragma unroll
    for (int p = 0; p < 2; ++p) {
        int r = p * 32 + grp;
        int v = row0 + r;
        uint4 o0 = make_uint4(0, 0, 0, 0), o1 = make_uint4(0, 0, 0, 0);
        if (v < N) {
            f32x2 acc[8];
            uint4 s = h4[(size_t)v * 8 + c];
#pragma unroll
            for (int j = 0; j < 8; ++j) acc[j] = (f32x2){0.f, 0.f};
            acc_fp8x4(acc[0], acc[1], s.x); acc_fp8x4(acc[2], acc[3], s.y);
            acc_fp8x4(acc[4], acc[5], s.z); acc_fp8x4(acc[6], acc[7], s.w);
            int e = rowp[v], end = rowp[v + 1];
            for (; e + 2 <= end; e += 2) {
                int u0 = colx[e];
                int u1 = colx[e + 1];
                uint4 r0 = h4[(size_t)u0 * 8 + c];
                uint4 r1 = h4[(size_t)u1 * 8 + c];
                acc_fp8x4(acc[0], acc[1], r0.x); acc_fp8x4(acc[2], acc[3], r0.y);
                acc_fp8x4(acc[4], acc[5], r0.z); acc_fp8x4(acc[6], acc[7], r0.w);
                acc_fp8x4(acc[0], acc[1], r1.x); acc_fp8x4(acc[2], acc[3], r1.y);
                acc_fp8x4(acc[4], acc[5], r1.z); acc_fp8x4(acc[6], acc[7], r1.w);
            }
            if (e < end) {
                int u = colx[e];
                uint4 rr = h4[(size_t)u * 8 + c];
                acc_fp8x4(acc[0], acc[1], rr.x); acc_fp8x4(acc[2], acc[3], rr.y);
                acc_fp8x4(acc[4], acc[5], rr.z); acc_fp8x4(acc[6], acc[7], rr.w);
            }
            float dv = dinv[v];
            o0.x = pack2(dv * acc[0].x, dv * acc[0].y);
            o0.y = pack2(dv * acc[1].x, dv * acc[1].y);
            o0.z = pack2(dv * acc[2].x, dv * acc[2].y);
            o0.w = pack2(dv * acc[3].x, dv * acc[3].y);
            o1.x = pack2(dv * acc[4].x, dv * acc[4].y);
            o1.y = pack2(dv * acc[5].x, dv * acc[5].y);
            o1.z = pack2(dv * acc[6].x, dv * acc[6].y);
            o1.w = pack2(dv * acc[7].x, dv * acc[7].y);
        }
        *(uint4*)&As[r][c * 16] = o0;
        *(uint4*)&As[r][c * 16 + 8] = o1;
    }
    __syncthreads();  // the only barrier

    // ---- MFMA phase ----
    int arow = w * 16 + (l & 15);
    int kblk = (l >> 4) * 8;
    f32x4 facc[8];
#pragma unroll
    for (int f = 0; f < 8; ++f) facc[f] = (f32x4){0.f, 0.f, 0.f, 0.f};

#pragma unroll
    for (int kk = 0; kk < 4; ++kk) {
        int k0 = kk * 32 + kblk;
        short8 a = *(const short8*)&As[arow][k0];
#pragma unroll
        for (int f = 0; f < 8; ++f) {
            int col = f * 16 + (l & 15);
            short8 bfr = *(const short8*)&WbT[(size_t)col * FDIM + k0];
            facc[f] = __builtin_amdgcn_mfma_f32_16x16x32_bf16(a, bfr, facc[f], 0, 0, 0);
        }
    }

    int rbase = w * 16 + (l >> 4) * 4;
    int cidx = l & 15;

    if constexpr (FP8OUT) {
        float dvr[4];
#pragma unroll
        for (int r = 0; r < 4; ++r) {
            int row = row0 + rbase + r;
            dvr[r] = (row < N) ? dinv[row] : 1.f;
        }
#pragma unroll
        for (int f = 0; f < 8; ++f) {
            int col = f * 16 + cidx;
            float bv = bias[col];
#pragma unroll
            for (int r = 0; r < 4; ++r) {
                float val = dvr[r] * fmaxf(facc[f][r] + bv, 0.f);
                unsigned pk = __builtin_amdgcn_cvt_pk_fp8_f32(val, 0.f, 0, false);
                As8[rbase + r][col] = (u8)(pk & 0xff);
            }
        }
        // wave-local coalesced store: 16 rows x 128B = 2 iters x 64 lanes x 16B
#pragma unroll
        for (int i = 0; i < 2; ++i) {
            int flat = i * 64 + l;
            int r = w * 16 + (flat >> 3);
            int ch = flat & 7;
            if (row0 + r < N)
                ((uint4*)(out8 + (size_t)(row0 + r) * FDIM))[ch] = *(const uint4*)&As8[r][ch * 16];
        }
    } else {
        // epilogue: relu(acc+b) -> bf16 into As (wave-local), coalesced store to outbf
#pragma unroll
        for (int f = 0; f < 8; ++f) {
            int col = f * 16 + cidx;
            float bv = bias[col];
#pragma unroll
            for (int r = 0; r < 4; ++r)
                As[rbase + r][col] = f2bf(fmaxf(facc[f][r] + bv, 0.f));
        }
#pragma unroll
        for (int i = 0; i < 4; ++i) {
            int r = w * 16 + (l >> 4) * 4 + i;
            int col = (l & 15) * 8;
            if (row0 + r < N) *(uint4*)&outbf[(size_t)(row0 + r) * FDIM + col] = *(const uint4*)&As[r][col];
        }
    }
}

// ---------------- pooling + classifier head + log_softmax ----------------

__global__ __launch_bounds__(512) void pool_head_kernel(const u16* __restrict__ h,
                                                        const int* __restrict__ batch, int N,
                                                        const float* __restrict__ Wo,
                                                        const float* __restrict__ bo,
                                                        float* __restrict__ out, int G) {
    int g = blockIdx.x;
    int tid = threadIdx.x;
    __shared__ int bounds[2];
    __shared__ float2 red[512];
    __shared__ float sp[128];
    __shared__ float lg[CDIM];
    __shared__ float sm[2];

    if (tid < 2) {
        int target = g + tid;
        int lo = 0, hi = N;
        while (lo < hi) {
            int mid = (lo + hi) >> 1;
            if (batch[mid] < target) lo = mid + 1; else hi = mid;
        }
        bounds[tid] = lo;
    }
    __syncthreads();
    int lo = bounds[0], hi = bounds[1];
    int cnt = hi - lo;

    int j = tid & 63;
    int rg = tid >> 6;
    const unsigned* h2 = (const unsigned*)h;
    float ax = 0.f, ay = 0.f;
    for (int r = lo + rg; r < hi; r += 8) {
        unsigned u = h2[(size_t)r * 64 + j];
        ax += __uint_as_float(u << 16);
        ay += __uint_as_float(u & 0xffff0000u);
    }
    red[tid] = make_float2(ax, ay);
    __syncthreads();
    if (tid < 64) {
        float sx = 0.f, sy = 0.f;
#pragma unroll
        for (int k = 0; k < 8; ++k) {
            float2 t = red[tid + 64 * k];
            sx += t.x; sy += t.y;
        }
        float inv = 1.f / (float)max(cnt, 1);
        sp[2 * tid] = sx * inv;
        sp[2 * tid + 1] = sy * inv;
    }
    __syncthreads();

    if (tid < CDIM) {
        float l = bo[tid];
        for (int k = 0; k < 128; ++k) l += sp[k] * Wo[(size_t)k * CDIM + tid];
        lg[tid] = l;
    }
    __syncthreads();
    if (tid == 0) {
        float m = -1e30f;
        for (int c = 0; c < CDIM; ++c) m = fmaxf(m, lg[c]);
        float ssum = 0.f;
        for (int c = 0; c < CDIM; ++c) ssum += expf(lg[c] - m);
        sm[0] = m;
        sm[1] = logf(ssum);
    }
    __syncthreads();
    if (tid < CDIM) out[(size_t)g * CDIM + tid] = lg[tid] - sm[0] - sm[1];
}

// ---------------- launch ----------------

extern "C" void kernel_launch(void* const* d_in, const int* in_sizes, int n_in,
                              void* d_out, int out_size, void* d_ws, size_t ws_size,
                              hipStream_t stream) {
    const float* x = (const float*)d_in[0];
    const int* edge = (const int*)d_in[1];      // int32 (harness converts integer inputs)
    const int* batch = (const int*)d_in[2];     // int32
    const float* W1 = (const float*)d_in[4];
    const float* b1 = (const float*)d_in[5];
    const float* W2 = (const float*)d_in[6];
    const float* b2 = (const float*)d_in[7];
    const float* W3 = (const float*)d_in[8];
    const float* b3 = (const float*)d_in[9];
    const float* Wo = (const float*)d_in[10];
    const float* bo = (const float*)d_in[11];

    int N = in_sizes[2];
    int E = in_sizes[1] / 2;
    int G = out_size / CDIM;
    const int* src = edge;
    const int* dst = edge + E;
    int NB = (N + 127) >> 7;   // 128-node buckets

    size_t off = 0;
    auto carve = [&](size_t bytes) -> size_t {
        size_t r = off;
        off += (bytes + 255) & ~(size_t)255;
        return r;
    };
    size_t o_h3   = carve((size_t)N * FDIM * 2);          // bf16 h3 (ebuf aliases here)
    size_t o_hs8A = carve((size_t)(N + 1) * FDIM);        // fp8 table A (row N = zeros)
    size_t o_hs8B = carve((size_t)(N + 1) * FDIM);        // fp8 table B (row N = zeros)
    size_t o_colx = carve((size_t)E * 4);
    size_t o_rowp = carve((size_t)(N + 1) * 4);
    size_t o_dinv = carve((size_t)N * 4);
    size_t o_bcnt = carve((size_t)NB * 4);
    size_t o_boff = carve((size_t)(NB + 1) * 4);
    size_t o_bcur = carve((size_t)NB * 4);
    size_t o_wbt  = carve((size_t)3 * 16384 * 2);

    bool ok = off <= ws_size && NB <= 1024 && N <= (1 << 25) &&
              (size_t)E * 4 <= (size_t)N * FDIM * 2;  // packed ebuf fits in h3 alias
    if (!ok) {
        sentinel_kernel<<<(out_size + 255) / 256, 256, 0, stream>>>((float*)d_out, out_size, 1234.5f);
        return;
    }

    char* base = (char*)d_ws;
    u16* h3bf  = (u16*)(base + o_h3);
    u8* hs8A   = (u8*)(base + o_hs8A);
    u8* hs8B   = (u8*)(base + o_hs8B);
    unsigned* ebuf = (unsigned*)(base + o_h3);  // alias: dead after build_kernel; h3 written by L3
    int* colx  = (int*)(base + o_colx);
    int* rowp  = (int*)(base + o_rowp);
    float* dinv = (float*)(base + o_dinv);
    int* bcnt  = (int*)(base + o_bcnt);
    int* boff  = (int*)(base + o_boff);
    int* bcur  = (int*)(base + o_bcur);
    u16* wbt   = (u16*)(base + o_wbt);

    int nchunk = (E + ECHUNK - 1) / ECHUNK;

    wconv_kernel<<<194, 256, 0, stream>>>(W1, W2, W3, wbt,
                                          (unsigned*)(hs8A + (size_t)N * FDIM),
                                          (unsigned*)(hs8B + (size_t)N * FDIM), bcnt, NB);
    count_kernel<<<nchunk, 256, 0, stream>>>(dst, E, bcnt, NB);
    scan_kernel<<<1, 1024, 0, stream>>>(bcnt, NB, E, boff, bcur);
    part_kernel<<<nchunk, 256, 0, stream>>>(src, dst, E, bcur, ebuf, NB);
    build_kernel<<<NB, 256, 0, stream>>>(ebuf, boff, rowp, dinv, colx, N, E);
    xconv_kernel<<<(N * FDIM / 4 + 255) / 256, 256, 0, stream>>>(x, dinv, hs8A, N);

    int layerBlocks = (N + 63) / 64;

    // L1: hs8A -> hs8B; L2: hs8B -> hs8A; L3: hs8A -> bf16 h3
    layer_kernel<true><<<layerBlocks, 256, 0, stream>>>(hs8A, rowp, colx, dinv, wbt, b1, hs8B, nullptr, N);
    layer_kernel<true><<<layerBlocks, 256, 0, stream>>>(hs8B, rowp, colx, dinv, wbt + 16384, b2, hs8A, nullptr, N);
    layer_kernel<false><<<layerBlocks, 256, 0, stream>>>(hs8A, rowp, colx, dinv, wbt + 32768, b3, nullptr, h3bf, N);

    pool_head_kernel<<<G, 512, 0, stream>>>(h3bf, batch, N, Wo, bo, (float*)d_out, G);
}